// Round 1
// baseline (188.639 us; speedup 1.0000x reference)
//
#include <hip/hip_runtime.h>
#include <cstdint>

// Problem dims (fixed by the reference)
#define B_DIM 16
#define T_DIM 1024
#define DK    512     // D_IN
#define H_DIM 1024
#define CCH   16      // scan chunks
#define LCH   64      // chunk length (CCH*LCH == T_DIM)

typedef __bf16 bf16x8 __attribute__((ext_vector_type(8)));
typedef __bf16 bf16x4 __attribute__((ext_vector_type(4)));
typedef float  f32x4  __attribute__((ext_vector_type(4)));

// ---- async global->LDS (16B per lane, wave-uniform LDS base + lane*16) ----
typedef __attribute__((address_space(1))) unsigned int* as1p;
typedef __attribute__((address_space(3))) unsigned int* as3p;

__device__ __forceinline__ void async_cp16(const void* g, void* l) {
  __builtin_amdgcn_global_load_lds((as1p)(uint64_t)g,
                                   (as3p)(uint32_t)(uint64_t)l, 16, 0, 0);
}

// ---- fp32 -> bf16 conversion, 4 elems/thread ----
__global__ __launch_bounds__(256) void cvt_f32_bf16(const float* __restrict__ in,
                                                    __bf16* __restrict__ out, int n4) {
  int i = blockIdx.x * 256 + threadIdx.x;
  if (i >= n4) return;
  f32x4 v = ((const f32x4*)in)[i];
  bf16x4 o;
  o.x = (__bf16)v.x; o.y = (__bf16)v.y; o.z = (__bf16)v.z; o.w = (__bf16)v.w;
  ((bf16x4*)out)[i] = o;
}

// ---- p[t,h] = a^(t+1), a = tanh(raw_a[h]); double-precision log/exp ----
__global__ __launch_bounds__(256) void compute_p(const float* __restrict__ raw_a,
                                                 float* __restrict__ p) {
  int h  = blockIdx.x * 256 + threadIdx.x;  // H/256 blocks in x
  int t0 = blockIdx.y * 64;                 // T/64 blocks in y
  float a = tanhf(raw_a[h]);
  double la = log((double)fabsf(a));        // a==0 -> -inf -> exp -> 0, correct
  bool neg = a < 0.f;
  for (int t = t0; t < t0 + 64; ++t) {
    float pv = (float)exp(la * (double)(t + 1));
    if (neg && ((t + 1) & 1)) pv = -pv;
    p[(size_t)t * H_DIM + h] = pv;
  }
}

// ---- bf16 MFMA GEMM (NT): z[m,n] = sum_k x[m,k] * W[n,k] + bias[n] ----
// 128x128 block tile, BK=32, 4 waves (2x2), each wave 64x64 via 4x4 MFMA 16x16x32.
__global__ __launch_bounds__(256) void gemm_bt(const __bf16* __restrict__ A,   // [M,K]
                                               const __bf16* __restrict__ Bw,  // [N,K]
                                               const float* __restrict__ bias, // [N]
                                               float* __restrict__ C) {        // [M,N]
  constexpr int N = H_DIM;
  constexpr int K = DK;

  __shared__ __align__(16) __bf16 As[128 * 32];
  __shared__ __align__(16) __bf16 Bs[128 * 32];

  const int tid  = threadIdx.x;
  const int wave = tid >> 6;
  const int lane = tid & 63;
  const int m0 = blockIdx.y * 128;
  const int n0 = blockIdx.x * 128;
  const int wm = wave >> 1;   // 0..1
  const int wn = wave & 1;    // 0..1

  const int lrow = lane >> 2;       // 0..15 within a 16-row group
  const int lk   = (lane & 3) * 8;  // k element offset: 0,8,16,24

  f32x4 acc[4][4];
#pragma unroll
  for (int i = 0; i < 4; ++i)
#pragma unroll
    for (int j = 0; j < 4; ++j) acc[i][j] = (f32x4){0.f, 0.f, 0.f, 0.f};

  for (int k0 = 0; k0 < K; k0 += 32) {
    __syncthreads();  // previous iteration's LDS reads done
#pragma unroll
    for (int q = 0; q < 2; ++q) {
      const int rbase = q * 64 + wave * 16;  // wave-uniform row group
      const __bf16* ga = A  + (size_t)(m0 + rbase + lrow) * K + k0 + lk;
      async_cp16(ga, As + rbase * 32);
      const __bf16* gb = Bw + (size_t)(n0 + rbase + lrow) * K + k0 + lk;
      async_cp16(gb, Bs + rbase * 32);
    }
    __syncthreads();  // drains vmcnt -> LDS tiles ready
#pragma unroll
    for (int i = 0; i < 4; ++i) {
      const bf16x8 af = *(const bf16x8*)(As + (wm * 64 + i * 16 + (lane & 15)) * 32 + (lane >> 4) * 8);
#pragma unroll
      for (int j = 0; j < 4; ++j) {
        const bf16x8 bf = *(const bf16x8*)(Bs + (wn * 64 + j * 16 + (lane & 15)) * 32 + (lane >> 4) * 8);
        acc[i][j] = __builtin_amdgcn_mfma_f32_16x16x32_bf16(af, bf, acc[i][j], 0, 0, 0);
      }
    }
  }

  // epilogue: C/D layout col=lane&15, row=(lane>>4)*4+r   [verified m89]
  const int cl = lane & 15;
  const int rq = (lane >> 4) * 4;
#pragma unroll
  for (int j = 0; j < 4; ++j) {
    const int col = n0 + wn * 64 + j * 16 + cl;
    const float bv = bias[col];
#pragma unroll
    for (int i = 0; i < 4; ++i) {
      const int rowg = m0 + wm * 64 + i * 16 + rq;
#pragma unroll
      for (int r = 0; r < 4; ++r) {
        C[(size_t)(rowg + r) * N + col] = acc[i][j][r] + bv;
      }
    }
  }
}

// ---- scan pass 1: per-(b,h) chunk sums of w = z / max(p,1e-12) ----
__global__ __launch_bounds__(256) void scan_pass1(const float* __restrict__ z,
                                                  const float* __restrict__ p,
                                                  float* __restrict__ S) {
  const int h = blockIdx.x * 256 + threadIdx.x;
  const int c = blockIdx.y;
  const int b = blockIdx.z;
  const size_t zb = ((size_t)b * T_DIM + c * LCH) * H_DIM + h;
  const size_t pb = (size_t)(c * LCH) * H_DIM + h;
  float s = 0.f;
  for (int t = 0; t < LCH; ++t) {
    float pv = fmaxf(p[pb + (size_t)t * H_DIM], 1e-12f);
    s += z[zb + (size_t)t * H_DIM] / pv;
  }
  S[((size_t)b * CCH + c) * H_DIM + h] = s;
}

// ---- scan pass 2: prefix + local cumsum; h = v*p + p*h0; degenerate mask ----
__global__ __launch_bounds__(256) void scan_pass2(const float* __restrict__ z,
                                                  const float* __restrict__ p,
                                                  const float* __restrict__ S,
                                                  const float* __restrict__ h0,
                                                  const float* __restrict__ raw_a,
                                                  float* __restrict__ out) {
  const int h = blockIdx.x * 256 + threadIdx.x;
  const int c = blockIdx.y;
  const int b = blockIdx.z;
  float prefix = 0.f;
  for (int cc = 0; cc < c; ++cc) prefix += S[((size_t)b * CCH + cc) * H_DIM + h];
  const float h0v = h0[(size_t)b * H_DIM + h];
  const float a = tanhf(raw_a[h]);
  const bool zm = fabsf(a) < 1e-6f;
  float v = prefix;
  const size_t base = ((size_t)b * T_DIM + c * LCH) * H_DIM + h;
  const size_t pb = (size_t)(c * LCH) * H_DIM + h;
  for (int t = 0; t < LCH; ++t) {
    const float zt = z[base + (size_t)t * H_DIM];
    const float pv = p[pb + (size_t)t * H_DIM];
    v += zt / fmaxf(pv, 1e-12f);
    const float hv = v * pv + pv * h0v;  // exactly ref's v*p + p*h0
    out[base + (size_t)t * H_DIM] = zm ? zt : hv;
  }
}

extern "C" void kernel_launch(void* const* d_in, const int* in_sizes, int n_in,
                              void* d_out, int out_size, void* d_ws, size_t ws_size,
                              hipStream_t stream) {
  const float* x     = (const float*)d_in[0];  // [B,T,DK]
  const float* h0    = (const float*)d_in[1];  // [B,H]
  const float* raw_a = (const float*)d_in[2];  // [H]
  const float* W     = (const float*)d_in[3];  // [H,DK]
  const float* bias  = (const float*)d_in[4];  // [H]
  float* out = (float*)d_out;                  // [B,T,H]

  char* ws = (char*)d_ws;
  float*  z  = (float*)(ws);                                         // 67108864 B
  __bf16* xb = (__bf16*)(ws + 67108864);                             // 16777216 B
  __bf16* wb = (__bf16*)(ws + 67108864 + 16777216);                  //  1048576 B
  float*  p  = (float*)(ws + 67108864 + 16777216 + 1048576);         //  4194304 B
  float*  S  = (float*)(ws + 67108864 + 16777216 + 1048576 + 4194304); // 1048576 B

  cvt_f32_bf16<<<(B_DIM * T_DIM * DK / 4 + 255) / 256, 256, 0, stream>>>(x, xb, B_DIM * T_DIM * DK / 4);
  cvt_f32_bf16<<<(H_DIM * DK / 4 + 255) / 256, 256, 0, stream>>>(W, wb, H_DIM * DK / 4);
  compute_p<<<dim3(H_DIM / 256, T_DIM / 64), 256, 0, stream>>>(raw_a, p);
  gemm_bt<<<dim3(H_DIM / 128, B_DIM * T_DIM / 128), 256, 0, stream>>>(xb, wb, bias, z);
  scan_pass1<<<dim3(H_DIM / 256, CCH, B_DIM), 256, 0, stream>>>(z, p, S);
  scan_pass2<<<dim3(H_DIM / 256, CCH, B_DIM), 256, 0, stream>>>(z, p, S, h0, raw_a, out);
}

// Round 2
// 153.657 us; speedup vs baseline: 1.2277x; 1.2277x over previous
//
#include <hip/hip_runtime.h>
#include <cstdint>

// Problem dims (fixed by the reference)
#define B_DIM 16
#define T_DIM 1024
#define DK    512     // D_IN
#define H_DIM 1024
#define CCH   16      // scan chunks
#define LCH   64      // chunk length (CCH*LCH == T_DIM)

typedef __bf16 bf16x8 __attribute__((ext_vector_type(8)));
typedef __bf16 bf16x4 __attribute__((ext_vector_type(4)));
typedef float  f32x4  __attribute__((ext_vector_type(4)));

// ---- async global->LDS (16B per lane, wave-uniform LDS base + lane*16) ----
typedef __attribute__((address_space(1))) unsigned int* as1p;
typedef __attribute__((address_space(3))) unsigned int* as3p;

__device__ __forceinline__ void async_cp16(const void* g, void* l) {
  __builtin_amdgcn_global_load_lds((as1p)(uint64_t)g,
                                   (as3p)(uint32_t)(uint64_t)l, 16, 0, 0);
}

// ---- fp32 -> bf16 conversion, 4 elems/thread ----
__global__ __launch_bounds__(256) void cvt_f32_bf16(const float* __restrict__ in,
                                                    __bf16* __restrict__ out, int n4) {
  int i = blockIdx.x * 256 + threadIdx.x;
  if (i >= n4) return;
  f32x4 v = ((const f32x4*)in)[i];
  bf16x4 o;
  o.x = (__bf16)v.x; o.y = (__bf16)v.y; o.z = (__bf16)v.z; o.w = (__bf16)v.w;
  ((bf16x4*)out)[i] = o;
}

// ---- per-h meta: {a, log2|a|, neg?, zero-mask?} ----
__global__ __launch_bounds__(256) void compute_meta(const float* __restrict__ raw_a,
                                                    float4* __restrict__ meta) {
  int h = blockIdx.x * 256 + threadIdx.x;
  if (h >= H_DIM) return;
  float a = tanhf(raw_a[h]);
  float la2 = log2f(fabsf(a));   // a==0 -> -inf; exp2f(-inf)=0, handled by zero-mask
  meta[h] = make_float4(a, la2, (a < 0.f) ? 1.f : 0.f, (fabsf(a) < 1e-6f) ? 1.f : 0.f);
}

// ---- bf16 MFMA GEMM (NT): z[m,n] = sum_k x[m,k]*W[n,k] + bias[n],
//      fused scan pass 1: S[b,c,n] = sum over chunk of z / max(p,1e-12). ----
// 128x128 block tile, BK=32, 4 waves (2x2), each wave 64x64 via 4x4 MFMA 16x16x32.
// Block rows = 128 consecutive t of one b = exactly 2 chunks of LCH=64 (wm split).
__global__ __launch_bounds__(256) void gemm_bt(const __bf16* __restrict__ A,   // [M,K]
                                               const __bf16* __restrict__ Bw,  // [N,K]
                                               const float* __restrict__ bias, // [N]
                                               const float4* __restrict__ meta,// [N]
                                               float* __restrict__ C,          // [M,N]
                                               float* __restrict__ S) {        // [B,CCH,N]
  constexpr int N = H_DIM;
  constexpr int K = DK;

  __shared__ __align__(16) __bf16 As[128 * 32];
  __shared__ __align__(16) __bf16 Bs[128 * 32];
  __shared__ float sred[2][128];

  const int tid  = threadIdx.x;
  const int wave = tid >> 6;
  const int lane = tid & 63;
  const int m0 = blockIdx.y * 128;
  const int n0 = blockIdx.x * 128;
  const int wm = wave >> 1;   // 0..1 (row half = chunk within block)
  const int wn = wave & 1;    // 0..1

  const int lrow = lane >> 2;       // 0..15 within a 16-row group
  const int lk   = (lane & 3) * 8;  // k element offset: 0,8,16,24

  f32x4 acc[4][4];
#pragma unroll
  for (int i = 0; i < 4; ++i)
#pragma unroll
    for (int j = 0; j < 4; ++j) acc[i][j] = (f32x4){0.f, 0.f, 0.f, 0.f};

  for (int k0 = 0; k0 < K; k0 += 32) {
    __syncthreads();  // previous iteration's LDS reads done
#pragma unroll
    for (int q = 0; q < 2; ++q) {
      const int rbase = q * 64 + wave * 16;  // wave-uniform row group
      const __bf16* ga = A  + (size_t)(m0 + rbase + lrow) * K + k0 + lk;
      async_cp16(ga, As + rbase * 32);
      const __bf16* gb = Bw + (size_t)(n0 + rbase + lrow) * K + k0 + lk;
      async_cp16(gb, Bs + rbase * 32);
    }
    __syncthreads();  // drains vmcnt -> LDS tiles ready
#pragma unroll
    for (int i = 0; i < 4; ++i) {
      const bf16x8 af = *(const bf16x8*)(As + (wm * 64 + i * 16 + (lane & 15)) * 32 + (lane >> 4) * 8);
#pragma unroll
      for (int j = 0; j < 4; ++j) {
        const bf16x8 bf = *(const bf16x8*)(Bs + (wn * 64 + j * 16 + (lane & 15)) * 32 + (lane >> 4) * 8);
        acc[i][j] = __builtin_amdgcn_mfma_f32_16x16x32_bf16(af, bf, acc[i][j], 0, 0, 0);
      }
    }
  }

  // epilogue: C/D layout col=lane&15, row=(lane>>4)*4+r   [verified m89]
  const int cl = lane & 15;
  const int rq = (lane >> 4) * 4;
  const int b = m0 >> 10;
  const int tloc0 = m0 & 1023;   // t of block row 0 within batch
#pragma unroll
  for (int j = 0; j < 4; ++j) {
    const int col = n0 + wn * 64 + j * 16 + cl;
    const float bv = bias[col];
    const float4 mt = meta[col];
    const float la2 = mt.y;
    const bool neg = mt.z != 0.f;
    float ssum = 0.f;
#pragma unroll
    for (int i = 0; i < 4; ++i) {
      const int rowg = wm * 64 + i * 16 + rq;
#pragma unroll
      for (int r = 0; r < 4; ++r) {
        const int tp1 = tloc0 + rowg + r + 1;
        const float zf = acc[i][j][r] + bv;
        C[(size_t)(m0 + rowg + r) * N + col] = zf;
        // 1/max(p,1e-12): p>0 -> min(2^-arg,1e12); p<0 (neg a, odd t+1) -> 1e12
        float inv = fminf(__builtin_amdgcn_exp2f(-la2 * (float)tp1), 1e12f);
        if (neg && (tp1 & 1)) inv = 1e12f;
        ssum += zf * inv;
      }
    }
    // lanes {cl, cl+16, cl+32, cl+48} hold partials for the same col
    ssum += __shfl_xor(ssum, 16, 64);
    ssum += __shfl_xor(ssum, 32, 64);
    if ((lane >> 4) == 0) sred[wm][wn * 64 + j * 16 + cl] = ssum;
  }
  __syncthreads();
  {
    const int g = tid >> 7;        // chunk half: 0..1
    const int col = tid & 127;
    S[((size_t)b * CCH + (tloc0 >> 6) + g) * H_DIM + n0 + col] = sred[g][col];
  }
}

// ---- scan pass 2: prefix(S) + local cumsum; h = v*p + p*h0; degenerate mask ----
__global__ __launch_bounds__(256) void scan_pass2(const float* __restrict__ z,
                                                  const float4* __restrict__ meta,
                                                  const float* __restrict__ S,
                                                  const float* __restrict__ h0,
                                                  float* __restrict__ out) {
  const int h = blockIdx.x * 256 + threadIdx.x;
  const int c = blockIdx.y;
  const int b = blockIdx.z;
  float prefix = 0.f;
  for (int cc = 0; cc < c; ++cc) prefix += S[((size_t)b * CCH + cc) * H_DIM + h];
  const float4 mt = meta[h];
  const float la2 = mt.y;
  const bool neg = mt.z != 0.f;
  const bool zm  = mt.w != 0.f;
  const float h0v = h0[(size_t)b * H_DIM + h];
  float v = prefix;
  const int t0 = c * LCH;
  const size_t base = ((size_t)b * T_DIM + t0) * H_DIM + h;
  for (int t = 0; t < LCH; ++t) {
    const float zt = z[base + (size_t)t * H_DIM];
    const int tp1 = t0 + t + 1;
    float pv = __builtin_amdgcn_exp2f(la2 * (float)tp1);   // |a|^(t+1)
    if (neg && (tp1 & 1)) pv = -pv;
    const float pc = fmaxf(pv, 1e-12f);                    // ref clamp semantics
    v += zt * __builtin_amdgcn_rcpf(pc);
    const float hv = v * pv + pv * h0v;                    // ref's v*p + p*h0
    out[base + (size_t)t * H_DIM] = zm ? zt : hv;
  }
}

extern "C" void kernel_launch(void* const* d_in, const int* in_sizes, int n_in,
                              void* d_out, int out_size, void* d_ws, size_t ws_size,
                              hipStream_t stream) {
  const float* x     = (const float*)d_in[0];  // [B,T,DK]
  const float* h0    = (const float*)d_in[1];  // [B,H]
  const float* raw_a = (const float*)d_in[2];  // [H]
  const float* W     = (const float*)d_in[3];  // [H,DK]
  const float* bias  = (const float*)d_in[4];  // [H]
  float* out = (float*)d_out;                  // [B,T,H]

  char* ws = (char*)d_ws;
  float*  z    = (float*)(ws);                                  // 67108864 B
  __bf16* xb   = (__bf16*)(ws + 67108864);                      // 16777216 B
  __bf16* wb   = (__bf16*)(ws + 67108864 + 16777216);           //  1048576 B
  float4* meta = (float4*)(ws + 67108864 + 16777216 + 1048576); //    16384 B
  float*  S    = (float*)(ws + 67108864 + 16777216 + 1048576 + 16384); // 1048576 B

  cvt_f32_bf16<<<(B_DIM * T_DIM * DK / 4 + 255) / 256, 256, 0, stream>>>(x, xb, B_DIM * T_DIM * DK / 4);
  cvt_f32_bf16<<<(H_DIM * DK / 4 + 255) / 256, 256, 0, stream>>>(W, wb, H_DIM * DK / 4);
  compute_meta<<<H_DIM / 256, 256, 0, stream>>>(raw_a, meta);
  gemm_bt<<<dim3(H_DIM / 128, B_DIM * T_DIM / 128), 256, 0, stream>>>(xb, wb, bias, meta, z, S);
  scan_pass2<<<dim3(H_DIM / 256, CCH, B_DIM), 256, 0, stream>>>(z, meta, S, h0, out);
}

// Round 3
// 146.737 us; speedup vs baseline: 1.2856x; 1.0472x over previous
//
#include <hip/hip_runtime.h>
#include <cstdint>

// Problem dims (fixed by the reference)
#define B_DIM 16
#define T_DIM 1024
#define DK    512     // D_IN
#define H_DIM 1024

typedef __bf16 bf16x8 __attribute__((ext_vector_type(8)));
typedef __bf16 bf16x4 __attribute__((ext_vector_type(4)));
typedef float  f32x4  __attribute__((ext_vector_type(4)));

// ---- async global->LDS (16B per lane, wave-uniform LDS base + lane*16) ----
typedef __attribute__((address_space(1))) unsigned int* as1p;
typedef __attribute__((address_space(3))) unsigned int* as3p;

__device__ __forceinline__ void async_cp16(const void* g, void* l) {
  __builtin_amdgcn_global_load_lds((as1p)(uint64_t)g,
                                   (as3p)(uint32_t)(uint64_t)l, 16, 0, 0);
}

// ---- fp32 -> bf16 conversion, 4 elems/thread ----
__global__ __launch_bounds__(256) void cvt_f32_bf16(const float* __restrict__ in,
                                                    __bf16* __restrict__ out, int n4) {
  int i = blockIdx.x * 256 + threadIdx.x;
  if (i >= n4) return;
  f32x4 v = ((const f32x4*)in)[i];
  bf16x4 o;
  o.x = (__bf16)v.x; o.y = (__bf16)v.y; o.z = (__bf16)v.z; o.w = (__bf16)v.w;
  ((bf16x4*)out)[i] = o;
}

// ---- per-h meta: {a, log2|a|, neg?, zero-mask?} ----
__global__ __launch_bounds__(256) void compute_meta(const float* __restrict__ raw_a,
                                                    float4* __restrict__ meta) {
  int h = blockIdx.x * 256 + threadIdx.x;
  if (h >= H_DIM) return;
  float a = tanhf(raw_a[h]);
  float la2 = log2f(fabsf(a));   // a==0 -> -inf; exp2f(-inf)=0, handled by zero-mask
  meta[h] = make_float4(a, la2, (a < 0.f) ? 1.f : 0.f, (fabsf(a) < 1e-6f) ? 1.f : 0.f);
}

// ---- fully fused: GEMM (z = x W^T + b) + weighted cumsum scan + output ----
// Grid: 512 blocks = (b = bid&15) x (strip = bid>>4, 32 cols each).
// Block: 256 thr, 4 waves. Block owns all T=1024 t of one b, 32 h-cols.
// 4 sequential m-chunks of 256 t; wave wm owns rows [wm*64,+64) = one LCH=64 chunk.
// Wave tile 64x32: i=0..3 (A frags), j=0..1 (B frags), 8 MFMA per kstep.
__global__ __launch_bounds__(256, 2) void fused_rnn(const __bf16* __restrict__ xb,  // [B*T, DK]
                                                    const __bf16* __restrict__ wb,  // [H, DK]
                                                    const float* __restrict__ bias, // [H]
                                                    const float4* __restrict__ meta,// [H]
                                                    const float* __restrict__ h0g,  // [B, H]
                                                    float* __restrict__ out) {      // [B*T, H]
  __shared__ __align__(16) __bf16 As[256 * 32];   // 16 KB
  __shared__ __align__(16) __bf16 Bs[32 * 32];    //  2 KB
  __shared__ float chunkTot[4][32];
  __shared__ float colCarry[32];

  const int tid  = threadIdx.x;
  const int wave = tid >> 6;
  const int lane = tid & 63;
  const int q = lane >> 4;     // 0..3
  const int c = lane & 15;     // 0..15

  const int b    = blockIdx.x & 15;
  const int n0   = (blockIdx.x >> 4) * 32;

  // per-lane column constants (2 cols per lane: j*16+c)
  float bias_j[2], la2_j[2], h0_j[2];
  bool neg_j[2], zm_j[2];
#pragma unroll
  for (int j = 0; j < 2; ++j) {
    const int col = n0 + j * 16 + c;
    bias_j[j] = bias[col];
    const float4 mt = meta[col];
    la2_j[j] = mt.y;
    neg_j[j] = mt.z != 0.f;
    zm_j[j]  = mt.w != 0.f;
    h0_j[j]  = h0g[(size_t)b * H_DIM + col];
  }

  if (tid < 32) colCarry[tid] = 0.f;

  const int srow = lane >> 2;        // staging row within 16-row group
  const int skof = (lane & 3) * 8;   // staging k-elem offset

  for (int mc = 0; mc < 4; ++mc) {
    const int t0 = mc * 256;
    const __bf16* Abase = xb + (size_t)(b * T_DIM + t0) * DK;

    f32x4 acc[4][2];
#pragma unroll
    for (int i = 0; i < 4; ++i)
#pragma unroll
      for (int j = 0; j < 2; ++j) acc[i][j] = (f32x4){0.f, 0.f, 0.f, 0.f};

    for (int k0 = 0; k0 < DK; k0 += 32) {
      __syncthreads();  // LDS buffers free (prev kstep reads / prev epilogue done)
#pragma unroll
      for (int r = 0; r < 4; ++r) {
        const int s = wave * 4 + r;                        // 16-row group 0..15
        const __bf16* ga = Abase + (size_t)(s * 16 + srow) * DK + k0 + skof;
        async_cp16(ga, As + s * 16 * 32);
      }
      if (wave < 2) {
        const __bf16* gb = wb + (size_t)(n0 + wave * 16 + srow) * DK + k0 + skof;
        async_cp16(gb, Bs + wave * 16 * 32);
      }
      __syncthreads();  // drain vmcnt -> tiles ready
      bf16x8 af[4], bfr[2];
#pragma unroll
      for (int i = 0; i < 4; ++i)
        af[i] = *(const bf16x8*)(As + (wave * 64 + i * 16 + c) * 32 + q * 8);
#pragma unroll
      for (int j = 0; j < 2; ++j)
        bfr[j] = *(const bf16x8*)(Bs + (j * 16 + c) * 32 + q * 8);
#pragma unroll
      for (int i = 0; i < 4; ++i)
#pragma unroll
        for (int j = 0; j < 2; ++j)
          acc[i][j] = __builtin_amdgcn_mfma_f32_16x16x32_bf16(af[i], bfr[j], acc[i][j], 0, 0, 0);
    }

    // ---- scan epilogue ----
    // acc[i][j][r] = z for t = t0 + wave*64 + i*16 + q*4 + r, col = n0 + j*16 + c
    // phase 1: per-lane w = z*inv(p); prefix within the wave's 64-t chunk
    f32x4 vloc[4][2];
    float icarry[2] = {0.f, 0.f};
#pragma unroll
    for (int i = 0; i < 4; ++i) {
#pragma unroll
      for (int j = 0; j < 2; ++j) {
        const float la2 = la2_j[j];
        f32x4 w;
#pragma unroll
        for (int r = 0; r < 4; ++r) {
          const int tp1 = t0 + wave * 64 + i * 16 + q * 4 + r + 1;
          const float z = acc[i][j][r] + bias_j[j];
          float inv = fminf(__builtin_amdgcn_exp2f(-la2 * (float)tp1), 1e12f);
          if (neg_j[j] && (tp1 & 1)) inv = 1e12f;
          w[r] = z * inv;
        }
        const float pr0 = w[0];
        const float pr1 = pr0 + w[1];
        const float pr2 = pr1 + w[2];
        const float pr3 = pr2 + w[3];
        const float x1 = __shfl_xor(pr3, 16, 64);  // q^1
        const float x2 = __shfl_xor(pr3, 32, 64);  // q^2
        const float x3 = __shfl_xor(pr3, 48, 64);  // q^3
        float sq = 0.f;
        if (q >= 2) sq += x2 + x3;
        if (q & 1) sq += x1;
        const float base = icarry[j] + sq;
        vloc[i][j] = (f32x4){base + pr0, base + pr1, base + pr2, base + pr3};
        icarry[j] += pr3 + x1 + x2 + x3;  // total over all 16 rows of group i
      }
    }
    if (q == 0) {
#pragma unroll
      for (int j = 0; j < 2; ++j) chunkTot[wave][j * 16 + c] = icarry[j];
    }
    __syncthreads();

    // phase 2: add cross-chunk carry, produce h, write out
    float cc[2];
#pragma unroll
    for (int j = 0; j < 2; ++j) {
      float s = colCarry[j * 16 + c];
      for (int w2 = 0; w2 < 4; ++w2)
        if (w2 < wave) s += chunkTot[w2][j * 16 + c];
      cc[j] = s;
    }
#pragma unroll
    for (int i = 0; i < 4; ++i) {
#pragma unroll
      for (int j = 0; j < 2; ++j) {
        const float la2 = la2_j[j];
        const int col = n0 + j * 16 + c;
#pragma unroll
        for (int r = 0; r < 4; ++r) {
          const int tl = t0 + wave * 64 + i * 16 + q * 4 + r;
          const int tp1 = tl + 1;
          float pv = __builtin_amdgcn_exp2f(la2 * (float)tp1);
          if (neg_j[j] && (tp1 & 1)) pv = -pv;
          const float v = cc[j] + vloc[i][j][r];
          const float hv = pv * v + pv * h0_j[j];
          const float zval = acc[i][j][r] + bias_j[j];
          out[(size_t)(b * T_DIM + tl) * H_DIM + col] = zm_j[j] ? zval : hv;
        }
      }
    }
    __syncthreads();  // all reads of colCarry/chunkTot done
    if (tid < 32)
      colCarry[tid] += chunkTot[0][tid] + chunkTot[1][tid] + chunkTot[2][tid] + chunkTot[3][tid];
    // next m-chunk's first k-loop barrier publishes the update
  }
}

extern "C" void kernel_launch(void* const* d_in, const int* in_sizes, int n_in,
                              void* d_out, int out_size, void* d_ws, size_t ws_size,
                              hipStream_t stream) {
  const float* x     = (const float*)d_in[0];  // [B,T,DK]
  const float* h0    = (const float*)d_in[1];  // [B,H]
  const float* raw_a = (const float*)d_in[2];  // [H]
  const float* W     = (const float*)d_in[3];  // [H,DK]
  const float* bias  = (const float*)d_in[4];  // [H]
  float* out = (float*)d_out;                  // [B,T,H]

  char* ws = (char*)d_ws;
  __bf16* xb   = (__bf16*)(ws);                        // 16777216 B
  __bf16* wb   = (__bf16*)(ws + 16777216);             //  1048576 B
  float4* meta = (float4*)(ws + 16777216 + 1048576);   //    16384 B

  cvt_f32_bf16<<<(B_DIM * T_DIM * DK / 4 + 255) / 256, 256, 0, stream>>>(x, xb, B_DIM * T_DIM * DK / 4);
  cvt_f32_bf16<<<(H_DIM * DK / 4 + 255) / 256, 256, 0, stream>>>(W, wb, H_DIM * DK / 4);
  compute_meta<<<H_DIM / 256, 256, 0, stream>>>(raw_a, meta);
  fused_rnn<<<512, 256, 0, stream>>>(xb, wb, bias, meta, h0, out);
}

// Round 4
// 137.747 us; speedup vs baseline: 1.3695x; 1.0653x over previous
//
#include <hip/hip_runtime.h>
#include <cstdint>

// Problem dims (fixed by the reference)
#define B_DIM 16
#define T_DIM 1024
#define DK    512     // D_IN
#define H_DIM 1024

typedef __bf16 bf16x8 __attribute__((ext_vector_type(8)));
typedef __bf16 bf16x4 __attribute__((ext_vector_type(4)));
typedef float  f32x4  __attribute__((ext_vector_type(4)));

// ---- async global->LDS (16B per lane, wave-uniform LDS base + lane*16) ----
typedef __attribute__((address_space(1))) unsigned int* as1p;
typedef __attribute__((address_space(3))) unsigned int* as3p;

__device__ __forceinline__ void async_cp16(const void* g, void* l) {
  __builtin_amdgcn_global_load_lds((as1p)(uint64_t)g,
                                   (as3p)(uint32_t)(uint64_t)l, 16, 0, 0);
}

// ---- fp32 -> bf16 conversion, 4 elems/thread ----
__global__ __launch_bounds__(256) void cvt_f32_bf16(const float* __restrict__ in,
                                                    __bf16* __restrict__ out, int n4) {
  int i = blockIdx.x * 256 + threadIdx.x;
  if (i >= n4) return;
  f32x4 v = ((const f32x4*)in)[i];
  bf16x4 o;
  o.x = (__bf16)v.x; o.y = (__bf16)v.y; o.z = (__bf16)v.z; o.w = (__bf16)v.w;
  ((bf16x4*)out)[i] = o;
}

// ---- per-h meta: {a, log2|a|, neg?, zero-mask?} ----
__global__ __launch_bounds__(256) void compute_meta(const float* __restrict__ raw_a,
                                                    float4* __restrict__ meta) {
  int h = blockIdx.x * 256 + threadIdx.x;
  if (h >= H_DIM) return;
  float a = tanhf(raw_a[h]);
  float la2 = log2f(fabsf(a));   // a==0 -> -inf; exp2f(-inf)=0, handled by zero-mask
  meta[h] = make_float4(a, la2, (a < 0.f) ? 1.f : 0.f, (fabsf(a) < 1e-6f) ? 1.f : 0.f);
}

// ---- fully fused: GEMM (z = x W^T + b) + weighted cumsum scan + output ----
// Grid: 512 blocks = (b = bid&15) x (strip = bid>>4, 32 cols).  b%8 pins the
// b-slice to one XCD's L2 (2 slices x 1MB + W 1MB < 4MB).
// Block: 256 thr, 4 waves; owns all T=1024 of one b; 4 sequential m-chunks of
// 256 t (wave wm = one LCH=64 scan chunk).  BK=64 (two 32-wide LDS tiles to
// keep the conflict-free bank pattern), LDS double-buffered, stage k+1 issued
// before compute on k; next m-chunk's k0 prefetched during the epilogue.
__global__ __launch_bounds__(256, 2) void fused_rnn(const __bf16* __restrict__ xb,  // [B*T, DK]
                                                    const __bf16* __restrict__ wb,  // [H, DK]
                                                    const float* __restrict__ bias, // [H]
                                                    const float4* __restrict__ meta,// [H]
                                                    const float* __restrict__ h0g,  // [B, H]
                                                    float* __restrict__ out) {      // [B*T, H]
  __shared__ __align__(16) __bf16 As[2][2][256][32];  // 64 KB  [buf][khalf][row][k]
  __shared__ __align__(16) __bf16 Bs[2][2][32][32];   //  8 KB
  __shared__ float chunkTot[4][32];
  __shared__ float colCarry[32];

  const int tid  = threadIdx.x;
  const int wave = tid >> 6;
  const int lane = tid & 63;
  const int q = lane >> 4;     // 0..3
  const int c = lane & 15;     // 0..15

  const int b  = blockIdx.x & 15;
  const int n0 = (blockIdx.x >> 4) * 32;

  // per-lane column constants (2 cols per lane: j*16+c)
  float bias_j[2], la2_j[2], h0_j[2];
  bool neg_j[2], zm_j[2];
#pragma unroll
  for (int j = 0; j < 2; ++j) {
    const int col = n0 + j * 16 + c;
    bias_j[j] = bias[col];
    const float4 mt = meta[col];
    la2_j[j] = mt.y;
    neg_j[j] = mt.z != 0.f;
    zm_j[j]  = mt.w != 0.f;
    h0_j[j]  = h0g[(size_t)b * H_DIM + col];
  }

  if (tid < 32) colCarry[tid] = 0.f;

  const int srow = lane >> 2;        // 0..15 row within a 16-row cp group
  const int skof = (lane & 3) * 8;   // k elem offset within 32-wide half

  const __bf16* const xbB = xb + (size_t)b * T_DIM * DK;

  // stage one BK=64 kstep (A: 256 rows, B: 32 rows) into buffer `buf`
  auto stage = [&](int t0, int k0, int buf) {
#pragma unroll
    for (int h = 0; h < 2; ++h) {
#pragma unroll
      for (int r = 0; r < 4; ++r) {
        const int rg = wave * 64 + r * 16;   // wave-uniform row group
        const __bf16* ga = xbB + (size_t)(t0 + rg + srow) * DK + k0 + h * 32 + skof;
        async_cp16(ga, &As[buf][h][rg][0]);
      }
    }
    {
      const int h = wave >> 1, rp = (wave & 1) * 16;
      const __bf16* gb = wb + (size_t)(n0 + rp + srow) * DK + k0 + (wave >> 1) * 32 + skof;
      async_cp16(gb, &Bs[buf][h][rp][0]);
    }
  };

  // prologue: stage chunk 0, kstep 0 into buf 0
  stage(0, 0, 0);
  __syncthreads();

  for (int mc = 0; mc < 4; ++mc) {
    const int t0 = mc * 256;

    f32x4 acc[4][2];
#pragma unroll
    for (int i = 0; i < 4; ++i)
#pragma unroll
      for (int j = 0; j < 2; ++j) acc[i][j] = (f32x4){0.f, 0.f, 0.f, 0.f};

    for (int k = 0; k < 8; ++k) {          // BK=64: 8 ksteps
      const int buf = k & 1;
      if (k < 7)       stage(t0, (k + 1) * 64, buf ^ 1);
      else if (mc < 3) stage(t0 + 256, 0, 0);   // prefetch next chunk's k0
#pragma unroll
      for (int ks = 0; ks < 2; ++ks) {
        bf16x8 af[4], bfr[2];
#pragma unroll
        for (int i = 0; i < 4; ++i)
          af[i] = *(const bf16x8*)(&As[buf][ks][wave * 64 + i * 16 + c][q * 8]);
#pragma unroll
        for (int j = 0; j < 2; ++j)
          bfr[j] = *(const bf16x8*)(&Bs[buf][ks][j * 16 + c][q * 8]);
#pragma unroll
        for (int i = 0; i < 4; ++i)
#pragma unroll
          for (int j = 0; j < 2; ++j)
            acc[i][j] = __builtin_amdgcn_mfma_f32_16x16x32_bf16(af[i], bfr[j], acc[i][j], 0, 0, 0);
      }
      __syncthreads();   // drains the stage issued this iter; protects buf reuse
    }

    // ---- scan epilogue ----
    // acc[i][j][r] = z for t = t0 + wave*64 + i*16 + q*4 + r, col = n0 + j*16 + c
    f32x4 vloc[4][2];
    float icarry[2] = {0.f, 0.f};
#pragma unroll
    for (int i = 0; i < 4; ++i) {
#pragma unroll
      for (int j = 0; j < 2; ++j) {
        const float la2 = la2_j[j];
        f32x4 w;
#pragma unroll
        for (int r = 0; r < 4; ++r) {
          const int tp1 = t0 + wave * 64 + i * 16 + q * 4 + r + 1;
          const float z = acc[i][j][r] + bias_j[j];
          float inv = fminf(__builtin_amdgcn_exp2f(-la2 * (float)tp1), 1e12f);
          if (neg_j[j] && (tp1 & 1)) inv = 1e12f;
          w[r] = z * inv;
        }
        const float pr0 = w[0];
        const float pr1 = pr0 + w[1];
        const float pr2 = pr1 + w[2];
        const float pr3 = pr2 + w[3];
        const float x1 = __shfl_xor(pr3, 16, 64);  // q^1
        const float x2 = __shfl_xor(pr3, 32, 64);  // q^2
        const float x3 = __shfl_xor(pr3, 48, 64);  // q^3
        float sq = 0.f;
        if (q >= 2) sq += x2 + x3;
        if (q & 1) sq += x1;
        const float base = icarry[j] + sq;
        vloc[i][j] = (f32x4){base + pr0, base + pr1, base + pr2, base + pr3};
        icarry[j] += pr3 + x1 + x2 + x3;  // total over all 16 rows of group i
      }
    }
    if (q == 0) {
#pragma unroll
      for (int j = 0; j < 2; ++j) chunkTot[wave][j * 16 + c] = icarry[j];
    }
    __syncthreads();

    // phase 2: add cross-chunk carry, produce h, write out
    float cc[2];
#pragma unroll
    for (int j = 0; j < 2; ++j) {
      float s = colCarry[j * 16 + c];
      for (int w2 = 0; w2 < 4; ++w2)
        if (w2 < wave) s += chunkTot[w2][j * 16 + c];
      cc[j] = s;
    }
#pragma unroll
    for (int i = 0; i < 4; ++i) {
#pragma unroll
      for (int j = 0; j < 2; ++j) {
        const float la2 = la2_j[j];
        const int col = n0 + j * 16 + c;
#pragma unroll
        for (int r = 0; r < 4; ++r) {
          const int tl = t0 + wave * 64 + i * 16 + q * 4 + r;
          const int tp1 = tl + 1;
          float pv = __builtin_amdgcn_exp2f(la2 * (float)tp1);
          if (neg_j[j] && (tp1 & 1)) pv = -pv;
          const float v = cc[j] + vloc[i][j][r];
          const float hv = pv * v + pv * h0_j[j];
          const float zval = acc[i][j][r] + bias_j[j];
          out[(size_t)(b * T_DIM + tl) * H_DIM + col] = zm_j[j] ? zval : hv;
        }
      }
    }
    __syncthreads();  // all reads of colCarry/chunkTot done
    if (tid < 32)
      colCarry[tid] += chunkTot[0][tid] + chunkTot[1][tid] + chunkTot[2][tid] + chunkTot[3][tid];
    // published by the barrier at the end of next chunk's first k-iteration
  }
}

extern "C" void kernel_launch(void* const* d_in, const int* in_sizes, int n_in,
                              void* d_out, int out_size, void* d_ws, size_t ws_size,
                              hipStream_t stream) {
  const float* x     = (const float*)d_in[0];  // [B,T,DK]
  const float* h0    = (const float*)d_in[1];  // [B,H]
  const float* raw_a = (const float*)d_in[2];  // [H]
  const float* W     = (const float*)d_in[3];  // [H,DK]
  const float* bias  = (const float*)d_in[4];  // [H]
  float* out = (float*)d_out;                  // [B,T,H]

  char* ws = (char*)d_ws;
  __bf16* xb   = (__bf16*)(ws);                        // 16777216 B
  __bf16* wb   = (__bf16*)(ws + 16777216);             //  1048576 B
  float4* meta = (float4*)(ws + 16777216 + 1048576);   //    16384 B

  cvt_f32_bf16<<<(B_DIM * T_DIM * DK / 4 + 255) / 256, 256, 0, stream>>>(x, xb, B_DIM * T_DIM * DK / 4);
  cvt_f32_bf16<<<(H_DIM * DK / 4 + 255) / 256, 256, 0, stream>>>(W, wb, H_DIM * DK / 4);
  compute_meta<<<H_DIM / 256, 256, 0, stream>>>(raw_a, meta);
  fused_rnn<<<512, 256, 0, stream>>>(xb, wb, bias, meta, h0, out);
}